// Round 1
// baseline (2150.182 us; speedup 1.0000x reference)
//
#include <hip/hip_runtime.h>
#include <hip/hip_bf16.h>
#include <math.h>

#define NB 128     // batch
#define NC 512     // channels
#define NT 40      // time steps
#define HW 512     // nH*nW
#define HL 256     // LSTM hidden per direction
#define NG 5000    // nclass
#define XDIM 1024  // 2*NC (GRU input)
#define G4 1024    // 4*HL
#define G3 1536    // 3*NC

// ---------------------------------------------------------------------------
// small setup kernels
// ---------------------------------------------------------------------------
__global__ void offsets_kernel(const int* __restrict__ tl, int* __restrict__ offs) {
  if (threadIdx.x == 0) {
    int o = 0;
    for (int b = 0; b < NB; ++b) { offs[b] = o; o += tl[b]; }
  }
}

__global__ void rowmap_kernel(const int* __restrict__ tl, const int* __restrict__ offs,
                              int* __restrict__ rowmap) {
  int b = blockIdx.x;
  int len = tl[b], off = offs[b];
  for (int t = threadIdx.x; t < len; t += blockDim.x)
    rowmap[off + t] = t * NB + b;   // row index into [t][b][*] matrices
}

__global__ void zero_kernel(float* __restrict__ p, int n) {
  int i = blockIdx.x * 256 + threadIdx.x;
  if (i < n) p[i] = 0.f;
}

// 1/sum over HW per (b,t)
__global__ __launch_bounds__(64) void asum_kernel(const float* __restrict__ A,
                                                  float* __restrict__ out) {
  int row = blockIdx.x;  // b*NT + t
  const float* p = A + (size_t)row * HW;
  float s = 0.f;
#pragma unroll
  for (int i = 0; i < 8; ++i) s += p[threadIdx.x + i * 64];
#pragma unroll
  for (int off = 32; off > 0; off >>= 1) s += __shfl_down(s, off);
  if (threadIdx.x == 0) out[row] = 1.0f / s;
}

// teacher-forcing embedding into x[:,:,512:1024]
__global__ __launch_bounds__(128) void emb_kernel(const float* __restrict__ ce,
                                                  const int* __restrict__ text,
                                                  const int* __restrict__ tl,
                                                  const int* __restrict__ offs,
                                                  float* __restrict__ x) {
  int bid = blockIdx.x;  // t*NB + b
  int t = bid >> 7, b = bid & 127;
  int tok = 0;
  if (t >= 2) {
    int p = t - 2;
    if (p < tl[b]) tok = text[offs[b] + p] + 1;
  }
  float4 v = *(const float4*)(ce + (size_t)tok * NC + threadIdx.x * 4);
  *(float4*)(x + (size_t)bid * XDIM + NC + threadIdx.x * 4) = v;
}

// ---------------------------------------------------------------------------
// generic f32 SGEMM: out[m][n] = sum_k Arow(m)[k] * B[n][k] * (bscale?bscale[n]:1)
//                    + (bias?bias[n]:0)
// A rows optionally gathered through rowmap. Batched via blockIdx.z strides.
// out address = out + b*Obstride + m*ldoM + n*ldoN  (supports transposed writes)
// 128x128 tile, 256 threads, 8x8 per thread, BK=16.
// ---------------------------------------------------------------------------
__global__ __launch_bounds__(256) void sgemm_kernel(
    int M, int N, int K,
    const float* __restrict__ A, int lda, long Abstride,
    const int* __restrict__ rowmap,
    const float* __restrict__ B, int ldb, long Bbstride,
    const float* __restrict__ bscale, int bscaleBstride,
    const float* __restrict__ bias,
    float* __restrict__ out, long ldoM, long ldoN, long Obstride) {
  const int batch = blockIdx.z;
  A += (long)batch * Abstride;
  B += (long)batch * Bbstride;
  out += (long)batch * Obstride;
  const float* bsc = bscale ? bscale + (long)batch * bscaleBstride : nullptr;

  __shared__ __align__(16) float As[16][132];  // [k][m], stride 132 (528B, 16B aligned)
  __shared__ __align__(16) float Bs[16][132];  // [k][n]

  const int m0 = blockIdx.y * 128, n0 = blockIdx.x * 128;
  const int tid = threadIdx.x;
  const int tm = tid >> 4, tn = tid & 15;
  const int r0 = tm * 8, c0 = tn * 8;
  float acc[8][8] = {};

  for (int k0 = 0; k0 < K; k0 += 16) {
#pragma unroll
    for (int it = 0; it < 2; ++it) {
      int ch = tid + it * 256;       // 0..511 float4 chunks
      int mm = ch >> 2;
      int kq = (ch & 3) << 2;
      int gm = m0 + mm;
      float4 v = make_float4(0.f, 0.f, 0.f, 0.f);
      if (gm < M) {
        long ar = rowmap ? (long)rowmap[gm] : (long)gm;
        v = *(const float4*)(A + ar * lda + k0 + kq);
      }
      As[kq + 0][mm] = v.x; As[kq + 1][mm] = v.y;
      As[kq + 2][mm] = v.z; As[kq + 3][mm] = v.w;
    }
#pragma unroll
    for (int it = 0; it < 2; ++it) {
      int ch = tid + it * 256;
      int nn = ch >> 2;
      int kq = (ch & 3) << 2;
      int gn = n0 + nn;
      float4 v = make_float4(0.f, 0.f, 0.f, 0.f);
      if (gn < N) {
        v = *(const float4*)(B + (long)gn * ldb + k0 + kq);
        if (bsc) { float s = bsc[gn]; v.x *= s; v.y *= s; v.z *= s; v.w *= s; }
      }
      Bs[kq + 0][nn] = v.x; Bs[kq + 1][nn] = v.y;
      Bs[kq + 2][nn] = v.z; Bs[kq + 3][nn] = v.w;
    }
    __syncthreads();
#pragma unroll
    for (int kk = 0; kk < 16; ++kk) {
      float a[8], bb[8];
      *(float4*)&a[0] = *(const float4*)&As[kk][r0];
      *(float4*)&a[4] = *(const float4*)&As[kk][r0 + 4];
      *(float4*)&bb[0] = *(const float4*)&Bs[kk][c0];
      *(float4*)&bb[4] = *(const float4*)&Bs[kk][c0 + 4];
#pragma unroll
      for (int i = 0; i < 8; ++i)
#pragma unroll
        for (int j = 0; j < 8; ++j) acc[i][j] += a[i] * bb[j];
    }
    __syncthreads();
  }
#pragma unroll
  for (int i = 0; i < 8; ++i) {
    int gm = m0 + r0 + i;
    if (gm >= M) continue;
#pragma unroll
    for (int j = 0; j < 8; ++j) {
      int gn = n0 + c0 + j;
      if (gn >= N) continue;
      float v = acc[i][j];
      if (bias) v += bias[gn];
      out[(long)gm * ldoM + (long)gn * ldoN] = v;
    }
  }
}

// ---------------------------------------------------------------------------
// LSTM step (both directions in one launch). grid = (HL/2, 2), 256 threads.
// Block owns j-chunk of 2; thread = (b, jj) computes all 4 gate dots + cell.
// ---------------------------------------------------------------------------
__device__ __forceinline__ float sigm(float x) { return 1.f / (1.f + expf(-x)); }

__global__ __launch_bounds__(256) void lstm_step_kernel(
    const float* __restrict__ xg_f, const float* __restrict__ xg_b,
    const float* __restrict__ Whh_f, const float* __restrict__ Whh_b,
    const float* __restrict__ bhh_f, const float* __restrict__ bhh_b,
    const float* __restrict__ hprev_f, float* __restrict__ hnew_f, float* __restrict__ c_f,
    const float* __restrict__ hprev_b, float* __restrict__ hnew_b, float* __restrict__ c_b,
    float* __restrict__ x, int step) {
  const int dir = blockIdx.y;
  const int t = dir ? (NT - 1 - step) : step;
  const float* xg = dir ? xg_b : xg_f;
  const float* Whh = dir ? Whh_b : Whh_f;
  const float* bhh = dir ? bhh_b : bhh_f;
  const float* hprev = dir ? hprev_b : hprev_f;
  float* hnew = dir ? hnew_b : hnew_f;
  float* cst = dir ? c_b : c_f;
  const int j0 = blockIdx.x * 2;

  __shared__ __align__(16) float Wl[8][256];  // rows: gate*2+jj
#pragma unroll
  for (int it = 0; it < 2; ++it) {
    int i = threadIdx.x + it * 256;  // float4 units, 512 total
    int r = i >> 6, k4 = i & 63;
    int gate = r >> 1, jj = r & 1;
    float4 v = *(const float4*)(Whh + (size_t)(gate * HL + j0 + jj) * HL + k4 * 4);
    *(float4*)&Wl[r][k4 * 4] = v;
  }
  __syncthreads();

  const int b = threadIdx.x & 127;
  const int jj = threadIdx.x >> 7;
  const float* hb = hprev + b * HL;
  float4 s0 = make_float4(0, 0, 0, 0), s1 = s0, s2 = s0, s3 = s0;
#pragma unroll 4
  for (int k4 = 0; k4 < 64; ++k4) {
    float4 hv = *(const float4*)(hb + k4 * 4);
    float4 w0 = *(const float4*)&Wl[0 + jj][k4 * 4];
    float4 w1 = *(const float4*)&Wl[2 + jj][k4 * 4];
    float4 w2 = *(const float4*)&Wl[4 + jj][k4 * 4];
    float4 w3 = *(const float4*)&Wl[6 + jj][k4 * 4];
    s0.x += hv.x * w0.x; s0.y += hv.y * w0.y; s0.z += hv.z * w0.z; s0.w += hv.w * w0.w;
    s1.x += hv.x * w1.x; s1.y += hv.y * w1.y; s1.z += hv.z * w1.z; s1.w += hv.w * w1.w;
    s2.x += hv.x * w2.x; s2.y += hv.y * w2.y; s2.z += hv.z * w2.z; s2.w += hv.w * w2.w;
    s3.x += hv.x * w3.x; s3.y += hv.y * w3.y; s3.z += hv.z * w3.z; s3.w += hv.w * w3.w;
  }
  const int j = j0 + jj;
  const long row = (long)t * NB + b;
  float gi = xg[row * G4 + 0 * HL + j] + (s0.x + s0.y + s0.z + s0.w) + bhh[0 * HL + j];
  float gf = xg[row * G4 + 1 * HL + j] + (s1.x + s1.y + s1.z + s1.w) + bhh[1 * HL + j];
  float gg = xg[row * G4 + 2 * HL + j] + (s2.x + s2.y + s2.z + s2.w) + bhh[2 * HL + j];
  float go = xg[row * G4 + 3 * HL + j] + (s3.x + s3.y + s3.z + s3.w) + bhh[3 * HL + j];
  float cold = cst[b * HL + j];
  float cn = sigm(gf) * cold + sigm(gi) * tanhf(gg);
  cst[b * HL + j] = cn;
  float hn = sigm(go) * tanhf(cn);
  hnew[b * HL + j] = hn;
  x[row * XDIM + dir * HL + j] = hn;  // fwd -> cols 0:256, bwd -> 256:512
}

// ---------------------------------------------------------------------------
// GRU step. grid = NC/2 blocks, 256 threads. thread = (b, jj).
// ---------------------------------------------------------------------------
__global__ __launch_bounds__(256) void gru_step_kernel(
    const float* __restrict__ xg, const float* __restrict__ Whh,
    const float* __restrict__ bhh, const float* __restrict__ hprev,
    float* __restrict__ hnew, float* __restrict__ gout, int t) {
  const int j0 = blockIdx.x * 2;
  __shared__ __align__(16) float Wl[6][512];  // rows gate*2+jj, gates r,z,n
#pragma unroll
  for (int it = 0; it < 3; ++it) {
    int i = threadIdx.x + it * 256;  // float4 units, 768 total
    int r = i >> 7, k4 = i & 127;
    int gate = r >> 1, jj = r & 1;
    float4 v = *(const float4*)(Whh + (size_t)(gate * NC + j0 + jj) * NC + k4 * 4);
    *(float4*)&Wl[r][k4 * 4] = v;
  }
  __syncthreads();

  const int b = threadIdx.x & 127;
  const int jj = threadIdx.x >> 7;
  const float* hb = hprev + b * NC;
  float4 s0 = make_float4(0, 0, 0, 0), s1 = s0, s2 = s0;
#pragma unroll 4
  for (int k4 = 0; k4 < 128; ++k4) {
    float4 hv = *(const float4*)(hb + k4 * 4);
    float4 w0 = *(const float4*)&Wl[0 + jj][k4 * 4];
    float4 w1 = *(const float4*)&Wl[2 + jj][k4 * 4];
    float4 w2 = *(const float4*)&Wl[4 + jj][k4 * 4];
    s0.x += hv.x * w0.x; s0.y += hv.y * w0.y; s0.z += hv.z * w0.z; s0.w += hv.w * w0.w;
    s1.x += hv.x * w1.x; s1.y += hv.y * w1.y; s1.z += hv.z * w1.z; s1.w += hv.w * w1.w;
    s2.x += hv.x * w2.x; s2.y += hv.y * w2.y; s2.z += hv.z * w2.z; s2.w += hv.w * w2.w;
  }
  const int j = j0 + jj;
  const long row = (long)t * NB + b;
  float hr = (s0.x + s0.y + s0.z + s0.w) + bhh[0 * NC + j];
  float hz = (s1.x + s1.y + s1.z + s1.w) + bhh[1 * NC + j];
  float hn = (s2.x + s2.y + s2.z + s2.w) + bhh[2 * NC + j];
  float xr = xg[row * G3 + 0 * NC + j];
  float xz = xg[row * G3 + 1 * NC + j];
  float xn = xg[row * G3 + 2 * NC + j];
  float r = sigm(xr + hr);
  float z = sigm(xz + hz);
  float n = tanhf(xn + r * hn);
  float hold = hprev[b * NC + j];
  float hv = (1.f - z) * n + z * hold;
  hnew[b * NC + j] = hv;
  gout[row * NC + j] = hv;
}

// ---------------------------------------------------------------------------
extern "C" void kernel_launch(void* const* d_in, const int* in_sizes, int n_in,
                              void* d_out, int out_size, void* d_ws, size_t ws_size,
                              hipStream_t stream) {
  const float* feature = (const float*)d_in[0];
  const float* A       = (const float*)d_in[1];
  const int*   text    = (const int*)d_in[2];
  const int*   tlen    = (const int*)d_in[3];
  const float* Wih_f   = (const float*)d_in[4];
  const float* Whh_f   = (const float*)d_in[5];
  const float* bih_f   = (const float*)d_in[6];
  const float* bhh_f   = (const float*)d_in[7];
  const float* Wih_b   = (const float*)d_in[8];
  const float* Whh_b   = (const float*)d_in[9];
  const float* bih_b   = (const float*)d_in[10];
  const float* bhh_b   = (const float*)d_in[11];
  const float* gWih    = (const float*)d_in[12];
  const float* gWhh    = (const float*)d_in[13];
  const float* gbih    = (const float*)d_in[14];
  const float* gbhh    = (const float*)d_in[15];
  const float* genW    = (const float*)d_in[16];
  const float* genb    = (const float*)d_in[17];
  const float* cemb    = (const float*)d_in[18];
  float* out = (float*)d_out;
  const int total = in_sizes[2];

  char* ws = (char*)d_ws;
  size_t off = 0;
  auto alloc = [&](size_t bytes) -> void* {
    void* p = ws + off;
    off += (bytes + 255) & ~(size_t)255;
    return p;
  };
  float* asum  = (float*)alloc((size_t)NB * NT * 4);
  int*   offs  = (int*)alloc(NB * 4);
  int*   rowmap= (int*)alloc((size_t)NB * NT * 4);
  float* Cbuf  = (float*)alloc((size_t)NT * NB * NC * 4);   // phase1: C; phase2: gru_out
  float* xgf   = (float*)alloc((size_t)NT * NB * G4 * 4);   // } reused as gru xg
  float* xgb   = (float*)alloc((size_t)NT * NB * G4 * 4);   // } (needs 31.5MB <= 42MB)
  float* xbuf  = (float*)alloc((size_t)NT * NB * XDIM * 4);
  float* hf    = (float*)alloc((size_t)2 * NB * HL * 4);
  float* cf    = (float*)alloc((size_t)NB * HL * 4);
  float* hb    = (float*)alloc((size_t)2 * NB * HL * 4);
  float* cb    = (float*)alloc((size_t)NB * HL * 4);
  float* gh    = (float*)alloc((size_t)2 * NB * NC * 4);
  float* gxg   = xgf;
  float* gout  = Cbuf;

  // --- setup ---
  offsets_kernel<<<1, 64, 0, stream>>>(tlen, offs);
  rowmap_kernel<<<NB, 64, 0, stream>>>(tlen, offs, rowmap);
  {
    int zn = (int)(((char*)gh - (char*)hf) / 4 + 2 * NB * NC);  // all states
    zero_kernel<<<(zn + 255) / 256, 256, 0, stream>>>(hf, zn);
  }
  asum_kernel<<<NB * NT, 64, 0, stream>>>(A, asum);

  // --- attention pooling: per-b GEMM, M=c(512), N=t(40), K=hw(512) ---
  // C[t,b,c] laid out [t][b][c]; out addr = b*NC + c*1 + t*(NB*NC)
  sgemm_kernel<<<dim3(1, 4, NB), 256, 0, stream>>>(
      NC, NT, HW,
      feature, HW, (long)NC * HW, nullptr,
      A, HW, (long)NT * HW,
      asum, NT,
      nullptr,
      Cbuf, 1L, (long)NB * NC, (long)NC);

  // --- LSTM input projections (both directions, plain time order) ---
  sgemm_kernel<<<dim3(G4 / 128, (NT * NB) / 128, 1), 256, 0, stream>>>(
      NT * NB, G4, NC, Cbuf, NC, 0, nullptr, Wih_f, NC, 0, nullptr, 0, bih_f,
      xgf, (long)G4, 1L, 0);
  sgemm_kernel<<<dim3(G4 / 128, (NT * NB) / 128, 1), 256, 0, stream>>>(
      NT * NB, G4, NC, Cbuf, NC, 0, nullptr, Wih_b, NC, 0, nullptr, 0, bih_b,
      xgb, (long)G4, 1L, 0);

  // --- LSTM recurrence (fwd+bwd fused per launch), writes x[:,:,0:512] ---
  for (int s = 0; s < NT; ++s) {
    lstm_step_kernel<<<dim3(HL / 2, 2), 256, 0, stream>>>(
        xgf, xgb, Whh_f, Whh_b, bhh_f, bhh_b,
        hf + (s & 1) * NB * HL, hf + ((s + 1) & 1) * NB * HL, cf,
        hb + (s & 1) * NB * HL, hb + ((s + 1) & 1) * NB * HL, cb,
        xbuf, s);
  }

  // --- embedding into x[:,:,512:1024] ---
  emb_kernel<<<NT * NB, 128, 0, stream>>>(cemb, text, tlen, offs, xbuf);

  // --- GRU input projection ---
  sgemm_kernel<<<dim3(G3 / 128, (NT * NB) / 128, 1), 256, 0, stream>>>(
      NT * NB, G3, XDIM, xbuf, XDIM, 0, nullptr, gWih, XDIM, 0, nullptr, 0, gbih,
      gxg, (long)G3, 1L, 0);

  // --- GRU recurrence ---
  for (int s = 0; s < NT; ++s) {
    gru_step_kernel<<<dim3(NC / 2), 256, 0, stream>>>(
        gxg, gWhh, gbhh, gh + (s & 1) * NB * NC, gh + ((s + 1) & 1) * NB * NC,
        gout, s);
  }

  // --- vocab projection, ragged-gathered rows straight into d_out ---
  sgemm_kernel<<<dim3((NG + 127) / 128, (total + 127) / 128, 1), 256, 0, stream>>>(
      total, NG, NC, gout, NC, 0, rowmap, genW, NC, 0, nullptr, 0, genb,
      out, (long)NG, 1L, 0);
}